// Round 8
// baseline (194.117 us; speedup 1.0000x reference)
//
#include <hip/hip_runtime.h>
#include <math.h>

// ExplaiNN fused forward: B=128, N=300, L=600, K=19, C1=100, PS=7
// LC=582, LP=83, NC=2
#define EPS_ 1e-5f

// ---------------------------------------------------------------------------
// kP: blocks 0..299: fc1_w[n][h][p] -> w1T[n][p][h] (per-n LDS transpose,
// pad 101, 33.5 KB LDS). Blocks 300..375: k = blk-300: cwT[k][n] =
// conv_w[n][k] (coalesced writes, short stride-76 gathers).
// ---------------------------------------------------------------------------
__global__ __launch_bounds__(256) void kP(const float* __restrict__ fc1w,
                                          const float* __restrict__ conv_w,
                                          float* __restrict__ w1T,
                                          float* __restrict__ cwT) {
    const int blk = blockIdx.x, tid = threadIdx.x;
    if (blk < 300) {
        __shared__ float sm[83 * 101];
        for (int i = tid; i < 8300; i += 256) {
            const int h = i / 83, p = i - h * 83;
            sm[p * 101 + h] = fc1w[(size_t)blk * 8300 + i];
        }
        __syncthreads();
        for (int i = tid; i < 8300; i += 256) {
            const int p = i / 100, h = i - p * 100;
            w1T[(size_t)blk * 8300 + i] = sm[p * 101 + h];
        }
    } else {
        const int k = blk - 300;            // 0..75
        for (int n = tid; n < 300; n += 256)
            cwT[k * 300 + n] = conv_w[n * 76 + k];
    }
}

// ---------------------------------------------------------------------------
// kA: conv1d(4ch,K=19) + bias + bn1 + exp + maxpool(7,7).
// R7 structure (loop-interchanged: persistent acc[4p x 7q], weights live one
// k-iter) but 4 WAVES PER WORKGROUP: R7's 64-thread blocks hit the per-CU
// workgroup-slot limit (Occupancy 38%, 45% latency stall). grid 128*32 x 256:
// id = b*32 + g (b-stride 32 == 0 mod 8 -> all b of one task-group on the
// same XCD -> pooled 64B lines assemble in local L2; R7-verified via clean
// WRITE_SIZE). wave w: sub = g*4 + w < 105; ng = sub/21, pc = sub%21.
// lane = n. x window wave-uniform -> s_loads; weights per-lane vector loads.
// ---------------------------------------------------------------------------
__global__ __launch_bounds__(256) void kA(
        const float* __restrict__ x,        // [128][4][600]
        const float* __restrict__ cwT,      // [76][300]
        const float* __restrict__ conv_b,
        const float* __restrict__ g1, const float* __restrict__ b1,
        const float* __restrict__ m1, const float* __restrict__ v1,
        float* __restrict__ pooled)         // [300][83][128]
{
    const int id  = blockIdx.x;             // b*32 + g
    const int b   = id >> 5;
    const int g   = id & 31;
    const int wv  = __builtin_amdgcn_readfirstlane(threadIdx.x >> 6);
    const int sub = g * 4 + wv;             // 0..127
    if (sub >= 105) return;                 // wave-uniform exit, no barriers
    const int ng  = sub / 21;
    const int pc  = sub - ng * 21;
    const int p0c = pc * 4;
    const int p0  = (p0c > 79) ? 79 : p0c;  // p=79 done twice, same value
    const int lane = threadIdx.x & 63;
    const int n   = ng * 64 + lane;
    const int nc  = (n < 300) ? n : 299;

    float acc[28];
    #pragma unroll
    for (int i = 0; i < 28; ++i) acc[i] = 0.f;

    #pragma unroll 1
    for (int c = 0; c < 4; ++c) {
        const float* xc = x + b * 2400 + c * 600 + 7 * p0;  // uniform -> s_load
        float xw[46];
        #pragma unroll
        for (int j = 0; j < 46; ++j) xw[j] = xc[j];
        const float* wc = cwT + c * 19 * 300 + nc;          // per-lane
        #pragma unroll
        for (int k = 0; k < 19; ++k) {
            const float wvv = wc[k * 300];  // one load, 28 FMAs, then dead
            #pragma unroll
            for (int p = 0; p < 4; ++p)
                #pragma unroll
                for (int q = 0; q < 7; ++q)
                    acc[p * 7 + q] = fmaf(xw[7 * p + q + k], wvv, acc[p * 7 + q]);
        }
    }

    const float A1 = g1[nc] * rsqrtf(v1[nc] + EPS_);
    const float B1 = fmaf(A1, conv_b[nc] - m1[nc], b1[nc]);
    if (n < 300) {
        float* op = pooled + ((size_t)n * 83 + p0) * 128 + b;
        #pragma unroll
        for (int p = 0; p < 4; ++p) {
            float mx = -INFINITY;           // exp monotone: max before exp
            #pragma unroll
            for (int q = 0; q < 7; ++q)
                mx = fmaxf(mx, fmaf(A1, acc[p * 7 + q], B1));
            op[p * 128] = __expf(mx);
        }
    }
}

// ---------------------------------------------------------------------------
// kB: fc1(K=83) + bn2 + relu + fc2 + bn3 + relu.
// grid 608 x 256: id = bh*304 + n (304%8==0 -> both halves of one n on the
// same XCD, w1T L2-shared). 4 waves: wave w owns h-chunk start {0,28,56,84}
// (16B-aligned -> dense s_load_dwordx4), sizes {28,28,28,16}. lane = b:
// pooled = 1 coalesced vector load per p; weights wave-uniform s_loads.
// acc[<=28]/lane -> fc2 partial in-thread -> 4x64 LDS combine.
// ---------------------------------------------------------------------------
__global__ __launch_bounds__(256) void kB(
        const float* __restrict__ pooled,   // [300][83][128]
        const float* __restrict__ w1T,      // [300][83][100]
        const float* __restrict__ fc1b,     // [300][100]
        const float* __restrict__ g2, const float* __restrict__ b2,
        const float* __restrict__ m2, const float* __restrict__ v2,
        const float* __restrict__ fc2w,     // [300][100]
        const float* __restrict__ fc2b,     // [300]
        const float* __restrict__ g3, const float* __restrict__ b3,
        const float* __restrict__ m3, const float* __restrict__ v3,
        float* __restrict__ sout)           // [300][128]
{
    __shared__ float sRed[4][64];
    const int id = blockIdx.x;              // bh*304 + n
    const int bh = id / 304;
    const int n  = id - bh * 304;
    const int tid  = threadIdx.x;
    const int lane = tid & 63;
    const int wv   = __builtin_amdgcn_readfirstlane(tid >> 6);  // uniform
    const int h0   = wv * 28;               // 0,28,56,84 (16B-aligned)
    const int nh   = (wv < 3) ? 28 : 16;
    const int bb   = bh * 64 + lane;

    float part = 0.f;
    if (n < 300) {
        const float* pp = pooled + (size_t)n * 83 * 128 + bb;   // per-lane
        const float* wp = w1T + (size_t)n * 8300 + h0;          // uniform

        float acc[28];
        #pragma unroll
        for (int j = 0; j < 28; ++j) acc[j] = 0.f;

        if (nh == 28) {
            #pragma unroll 2
            for (int p = 0; p < 83; ++p) {
                const float pv = pp[p * 128];                   // coalesced
                #pragma unroll
                for (int j = 0; j < 28; ++j)
                    acc[j] = fmaf(pv, wp[p * 100 + j], acc[j]); // v,s,v
            }
        } else {
            #pragma unroll 2
            for (int p = 0; p < 83; ++p) {
                const float pv = pp[p * 128];
                #pragma unroll
                for (int j = 0; j < 16; ++j)
                    acc[j] = fmaf(pv, wp[p * 100 + j], acc[j]);
            }
        }

        const int base = n * 100 + h0;                          // uniform
        for (int j = 0; j < nh; ++j) {
            const float A2 = g2[base + j] * rsqrtf(v2[base + j] + EPS_);
            const float C2 = fmaf(A2, fc1b[base + j] - m2[base + j], b2[base + j]);
            const float act = fmaxf(fmaf(A2, acc[j], C2), 0.f);
            part = fmaf(act, fc2w[base + j], part);
        }
    }
    sRed[wv][lane] = part;
    __syncthreads();
    if (tid < 64 && n < 300) {
        float s = sRed[0][tid] + sRed[1][tid] + sRed[2][tid] + sRed[3][tid];
        s += fc2b[n];
        const float A3 = g3[n] * rsqrtf(v3[n] + EPS_);
        const float z = fmaf(A3, s - m3[n], b3[n]);
        sout[n * 128 + bh * 64 + tid] = fmaxf(z, 0.f);
    }
}

// ---------------------------------------------------------------------------
// kC: out[b,c] = sum_n sout[n][b] * fw[c][n] + fb[c].  grid 128 x 64.
// ---------------------------------------------------------------------------
__global__ __launch_bounds__(64) void kC(
        const float* __restrict__ sout,     // [300][128]
        const float* __restrict__ fw,       // [2][300]
        const float* __restrict__ fb,
        float* __restrict__ out)            // [128][2]
{
    const int b = blockIdx.x, t = threadIdx.x;
    float a0 = 0.f, a1 = 0.f;
    for (int nn = t; nn < 300; nn += 64) {
        const float v = sout[nn * 128 + b];
        a0 = fmaf(v, fw[nn], a0);
        a1 = fmaf(v, fw[300 + nn], a1);
    }
    #pragma unroll
    for (int off = 32; off > 0; off >>= 1) {
        a0 += __shfl_xor(a0, off, 64);
        a1 += __shfl_xor(a1, off, 64);
    }
    if (t == 0) {
        out[b * 2 + 0] = a0 + fb[0];
        out[b * 2 + 1] = a1 + fb[1];
    }
}

extern "C" void kernel_launch(void* const* d_in, const int* in_sizes, int n_in,
                              void* d_out, int out_size, void* d_ws, size_t ws_size,
                              hipStream_t stream) {
    const float* x      = (const float*)d_in[0];
    const float* conv_w = (const float*)d_in[1];
    const float* conv_b = (const float*)d_in[2];
    const float* g1 = (const float*)d_in[3];
    const float* b1 = (const float*)d_in[4];
    const float* m1 = (const float*)d_in[5];
    const float* v1 = (const float*)d_in[6];
    const float* fc1_w = (const float*)d_in[7];
    const float* fc1_b = (const float*)d_in[8];
    const float* g2 = (const float*)d_in[9];
    const float* b2 = (const float*)d_in[10];
    const float* m2 = (const float*)d_in[11];
    const float* v2 = (const float*)d_in[12];
    const float* fc2_w = (const float*)d_in[13];
    const float* fc2_b = (const float*)d_in[14];
    const float* g3 = (const float*)d_in[15];
    const float* b3 = (const float*)d_in[16];
    const float* m3 = (const float*)d_in[17];
    const float* v3 = (const float*)d_in[18];
    const float* fw = (const float*)d_in[19];
    const float* fb = (const float*)d_in[20];
    float* out = (float*)d_out;

    float* pooled = (float*)d_ws;                        // 300*83*128 = 3187200
    float* w1T    = pooled + (size_t)300 * 83 * 128;     // 300*8300   = 2490000
    float* cwT    = w1T + (size_t)300 * 8300;            // 76*300     = 22800
    float* sout   = cwT + 22800;                         // 300*128    = 38400
    // total ws: ~23 MB

    kP<<<376, 256, 0, stream>>>(fc1_w, conv_w, w1T, cwT);
    kA<<<128 * 32, 256, 0, stream>>>(x, cwT, conv_b, g1, b1, m1, v1, pooled);
    kB<<<608, 256, 0, stream>>>(pooled, w1T, fc1_b, g2, b2, m2, v2,
                                fc2_w, fc2_b, g3, b3, m3, v3, sout);
    kC<<<128, 64, 0, stream>>>(sout, fw, fb, out);
}

// Round 9
// 187.164 us; speedup vs baseline: 1.0371x; 1.0371x over previous
//
#include <hip/hip_runtime.h>
#include <math.h>

// ExplaiNN fused forward: B=128, N=300, L=600, K=19, C1=100, PS=7
// LC=582, LP=83, NC=2
#define EPS_ 1e-5f

// ---------------------------------------------------------------------------
// kP: blocks 0..299: fc1_w[n][h][p] -> w1T[n][p][h] (per-n LDS transpose,
// pad 101, 33.5 KB LDS). Blocks 300..319: (c,kq) = blk-300: pack conv
// weights cw4[c][kq][n][0..3] = conv_w[n][c*19 + 4*kq+i] (i<19 else 0):
// float4-per-lane layout so kA fetches 4 k's in ONE coalesced 16B load.
// ---------------------------------------------------------------------------
__global__ __launch_bounds__(256) void kP(const float* __restrict__ fc1w,
                                          const float* __restrict__ conv_w,
                                          float* __restrict__ w1T,
                                          float* __restrict__ cw4) {
    const int blk = blockIdx.x, tid = threadIdx.x;
    if (blk < 300) {
        __shared__ float sm[83 * 101];
        for (int i = tid; i < 8300; i += 256) {
            const int h = i / 83, p = i - h * 83;
            sm[p * 101 + h] = fc1w[(size_t)blk * 8300 + i];
        }
        __syncthreads();
        for (int i = tid; i < 8300; i += 256) {
            const int p = i / 100, h = i - p * 100;
            w1T[(size_t)blk * 8300 + i] = sm[p * 101 + h];
        }
    } else {
        const int cq = blk - 300;           // 0..19
        const int c  = cq / 5;
        const int kq = cq - c * 5;
        for (int n = tid; n < 300; n += 256) {
            float4 v;
            const int k0 = 4 * kq;
            v.x = (k0 + 0 < 19) ? conv_w[n * 76 + c * 19 + k0 + 0] : 0.f;
            v.y = (k0 + 1 < 19) ? conv_w[n * 76 + c * 19 + k0 + 1] : 0.f;
            v.z = (k0 + 2 < 19) ? conv_w[n * 76 + c * 19 + k0 + 2] : 0.f;
            v.w = (k0 + 3 < 19) ? conv_w[n * 76 + c * 19 + k0 + 3] : 0.f;
            reinterpret_cast<float4*>(cw4)[(c * 5 + kq) * 300 + n] = v;
        }
    }
}

// ---------------------------------------------------------------------------
// kA: conv1d(4ch,K=19) + bias + bn1 + exp + maxpool(7,7).
// R7 loop-interchanged structure (persistent acc[4p x 7q]; R7=47us) with the
// weight stream cut 4x: cw4 float4-per-lane packing -> 20 coalesced 16B
// loads per task (vs 76 dword loads), each feeding 112 FMAs (224 issue cy)
// -> latency self-hiding at ~3 waves/SIMD. R8 showed occupancy is NOT
// WG-slot-bound (4-wave WGs: 47->54us), so back to 64-thread blocks.
// grid 128*112 x 64: id = b*112+sub (112%8==0 -> same-XCD pooled lines,
// verified clean WRITE_SIZE since R5). lane = n; x window uniform s_loads.
// ---------------------------------------------------------------------------
__global__ __launch_bounds__(64) void kA(
        const float* __restrict__ x,        // [128][4][600]
        const float* __restrict__ cw4,      // [4][5][300][4]
        const float* __restrict__ conv_b,
        const float* __restrict__ g1, const float* __restrict__ b1,
        const float* __restrict__ m1, const float* __restrict__ v1,
        float* __restrict__ pooled)         // [300][83][128]
{
    const int id  = blockIdx.x;             // b*112 + sub
    const int b   = id / 112;
    const int sub = id - b * 112;
    if (sub >= 105) return;
    const int ng  = sub / 21;
    const int pc  = sub - ng * 21;
    const int p0c = pc * 4;
    const int p0  = (p0c > 79) ? 79 : p0c;  // p=79 done twice, same value
    const int lane = threadIdx.x;
    const int n   = ng * 64 + lane;
    const int nc  = (n < 300) ? n : 299;

    const float4* w4 = reinterpret_cast<const float4*>(cw4);

    float acc[28];
    #pragma unroll
    for (int i = 0; i < 28; ++i) acc[i] = 0.f;

    #pragma unroll 1
    for (int c = 0; c < 4; ++c) {
        const float* xc = x + b * 2400 + c * 600 + 7 * p0;  // uniform -> s_load
        float xw[46];
        #pragma unroll
        for (int j = 0; j < 46; ++j) xw[j] = xc[j];
        #pragma unroll
        for (int kq = 0; kq < 5; ++kq) {
            const float4 wv = w4[(c * 5 + kq) * 300 + nc];  // 4 k's, coalesced
            const int ni = (kq == 4) ? 3 : 4;               // k<19
            #pragma unroll
            for (int i = 0; i < ni; ++i) {
                const int k = 4 * kq + i;
                const float wvv = (i == 0) ? wv.x : (i == 1) ? wv.y
                                : (i == 2) ? wv.z : wv.w;
                #pragma unroll
                for (int p = 0; p < 4; ++p)
                    #pragma unroll
                    for (int q = 0; q < 7; ++q)
                        acc[p * 7 + q] = fmaf(xw[7 * p + q + k], wvv,
                                              acc[p * 7 + q]);
            }
        }
    }

    const float A1 = g1[nc] * rsqrtf(v1[nc] + EPS_);
    const float B1 = fmaf(A1, conv_b[nc] - m1[nc], b1[nc]);
    if (n < 300) {
        float* op = pooled + ((size_t)n * 83 + p0) * 128 + b;
        #pragma unroll
        for (int p = 0; p < 4; ++p) {
            float mx = -INFINITY;           // exp monotone: max before exp
            #pragma unroll
            for (int q = 0; q < 7; ++q)
                mx = fmaxf(mx, fmaf(A1, acc[p * 7 + q], B1));
            op[p * 128] = __expf(mx);
        }
    }
}

// ---------------------------------------------------------------------------
// kB: fc1(K=83) + bn2 + relu + fc2 + bn3 + relu.  (R8 structure, kept)
// grid 608 x 256: id = bh*304 + n. 4 waves: wave w owns h-chunk start
// {0,28,56,84} (16B-aligned -> dense s_load), sizes {28,28,28,16}. lane = b:
// pooled = 1 coalesced vector load per p; weights wave-uniform s_loads.
// acc[<=28]/lane -> fc2 partial in-thread -> 4x64 LDS combine.
// ---------------------------------------------------------------------------
__global__ __launch_bounds__(256) void kB(
        const float* __restrict__ pooled,   // [300][83][128]
        const float* __restrict__ w1T,      // [300][83][100]
        const float* __restrict__ fc1b,     // [300][100]
        const float* __restrict__ g2, const float* __restrict__ b2,
        const float* __restrict__ m2, const float* __restrict__ v2,
        const float* __restrict__ fc2w,     // [300][100]
        const float* __restrict__ fc2b,     // [300]
        const float* __restrict__ g3, const float* __restrict__ b3,
        const float* __restrict__ m3, const float* __restrict__ v3,
        float* __restrict__ sout)           // [300][128]
{
    __shared__ float sRed[4][64];
    const int id = blockIdx.x;              // bh*304 + n
    const int bh = id / 304;
    const int n  = id - bh * 304;
    const int tid  = threadIdx.x;
    const int lane = tid & 63;
    const int wv   = __builtin_amdgcn_readfirstlane(tid >> 6);  // uniform
    const int h0   = wv * 28;               // 0,28,56,84 (16B-aligned)
    const int nh   = (wv < 3) ? 28 : 16;
    const int bb   = bh * 64 + lane;

    float part = 0.f;
    if (n < 300) {
        const float* pp = pooled + (size_t)n * 83 * 128 + bb;   // per-lane
        const float* wp = w1T + (size_t)n * 8300 + h0;          // uniform

        float acc[28];
        #pragma unroll
        for (int j = 0; j < 28; ++j) acc[j] = 0.f;

        if (nh == 28) {
            #pragma unroll 2
            for (int p = 0; p < 83; ++p) {
                const float pv = pp[p * 128];                   // coalesced
                #pragma unroll
                for (int j = 0; j < 28; ++j)
                    acc[j] = fmaf(pv, wp[p * 100 + j], acc[j]); // v,s,v
            }
        } else {
            #pragma unroll 2
            for (int p = 0; p < 83; ++p) {
                const float pv = pp[p * 128];
                #pragma unroll
                for (int j = 0; j < 16; ++j)
                    acc[j] = fmaf(pv, wp[p * 100 + j], acc[j]);
            }
        }

        const int base = n * 100 + h0;                          // uniform
        for (int j = 0; j < nh; ++j) {
            const float A2 = g2[base + j] * rsqrtf(v2[base + j] + EPS_);
            const float C2 = fmaf(A2, fc1b[base + j] - m2[base + j], b2[base + j]);
            const float act = fmaxf(fmaf(A2, acc[j], C2), 0.f);
            part = fmaf(act, fc2w[base + j], part);
        }
    }
    sRed[wv][lane] = part;
    __syncthreads();
    if (tid < 64 && n < 300) {
        float s = sRed[0][tid] + sRed[1][tid] + sRed[2][tid] + sRed[3][tid];
        s += fc2b[n];
        const float A3 = g3[n] * rsqrtf(v3[n] + EPS_);
        const float z = fmaf(A3, s - m3[n], b3[n]);
        sout[n * 128 + bh * 64 + tid] = fmaxf(z, 0.f);
    }
}

// ---------------------------------------------------------------------------
// kC: out[b,c] = sum_n sout[n][b] * fw[c][n] + fb[c].  grid 128 x 64.
// ---------------------------------------------------------------------------
__global__ __launch_bounds__(64) void kC(
        const float* __restrict__ sout,     // [300][128]
        const float* __restrict__ fw,       // [2][300]
        const float* __restrict__ fb,
        float* __restrict__ out)            // [128][2]
{
    const int b = blockIdx.x, t = threadIdx.x;
    float a0 = 0.f, a1 = 0.f;
    for (int nn = t; nn < 300; nn += 64) {
        const float v = sout[nn * 128 + b];
        a0 = fmaf(v, fw[nn], a0);
        a1 = fmaf(v, fw[300 + nn], a1);
    }
    #pragma unroll
    for (int off = 32; off > 0; off >>= 1) {
        a0 += __shfl_xor(a0, off, 64);
        a1 += __shfl_xor(a1, off, 64);
    }
    if (t == 0) {
        out[b * 2 + 0] = a0 + fb[0];
        out[b * 2 + 1] = a1 + fb[1];
    }
}

extern "C" void kernel_launch(void* const* d_in, const int* in_sizes, int n_in,
                              void* d_out, int out_size, void* d_ws, size_t ws_size,
                              hipStream_t stream) {
    const float* x      = (const float*)d_in[0];
    const float* conv_w = (const float*)d_in[1];
    const float* conv_b = (const float*)d_in[2];
    const float* g1 = (const float*)d_in[3];
    const float* b1 = (const float*)d_in[4];
    const float* m1 = (const float*)d_in[5];
    const float* v1 = (const float*)d_in[6];
    const float* fc1_w = (const float*)d_in[7];
    const float* fc1_b = (const float*)d_in[8];
    const float* g2 = (const float*)d_in[9];
    const float* b2 = (const float*)d_in[10];
    const float* m2 = (const float*)d_in[11];
    const float* v2 = (const float*)d_in[12];
    const float* fc2_w = (const float*)d_in[13];
    const float* fc2_b = (const float*)d_in[14];
    const float* g3 = (const float*)d_in[15];
    const float* b3 = (const float*)d_in[16];
    const float* m3 = (const float*)d_in[17];
    const float* v3 = (const float*)d_in[18];
    const float* fw = (const float*)d_in[19];
    const float* fb = (const float*)d_in[20];
    float* out = (float*)d_out;

    float* pooled = (float*)d_ws;                        // 300*83*128 = 3187200
    float* w1T    = pooled + (size_t)300 * 83 * 128;     // 300*8300   = 2490000
    float* cw4    = w1T + (size_t)300 * 8300;            // 4*5*300*4  = 24000
    float* sout   = cw4 + 24000;                         // 300*128    = 38400
    // total ws: ~23 MB

    kP<<<320, 256, 0, stream>>>(fc1_w, conv_w, w1T, cw4);
    kA<<<128 * 112, 64, 0, stream>>>(x, cw4, conv_b, g1, b1, m1, v1, pooled);
    kB<<<608, 256, 0, stream>>>(pooled, w1T, fc1_b, g2, b2, m2, v2,
                                fc2_w, fc2_b, g3, b3, m3, v3, sout);
    kC<<<128, 64, 0, stream>>>(sout, fw, fb, out);
}